// Round 16
// baseline (46.569 us; speedup 1.0000x reference)
//
#include <hip/hip_runtime.h>
#include <hip/hip_bf16.h>
#include <math.h>
#include <string.h>

#define NPTS 524288
#define KC 32
#define DIM 64
#define NTILES 4096        // NPTS / 128 points per block-tile
#define PROW 4128          // partial row: 32 dem + 32*128 rx
#define GRIDX 768          // 3 blocks/CU resident (LDS 49280*3 <= 160KiB, VGPR 128 -> 4 ok)

typedef __attribute__((ext_vector_type(8)))  short short8v;
typedef __attribute__((ext_vector_type(16))) float f32x16;

// LDS byte map (per block), total 49280 B:
//   xt  @0      [128 pt][256B]  byte = pt*256  + (colB ^ ((pt&15)<<4))    (bf16 x | x^2)
//   rl  @32768  [32 comp][256B] byte = comp*256 + ((pt*2) ^ ((comp&15)<<4)) (bf16 r)
//   Wl  @40960  [32 comp][256B] byte = comp*256 + ((k*2) ^ ((comp&15)<<4))  (bf16 W)
//   cl  @49152  float[32]
// prologue: clp[256] scratch overlays xt[0..1024)
#define RL_BASE  32768
#define WL_BASE  40960
#define CL_BASE  49152
#define SMEM_BYTES 49280

__device__ __forceinline__ unsigned short s2bf(float a) {
    __hip_bfloat16 h = __float2bfloat16(a);
    unsigned short u;
    memcpy(&u, &h, 2);
    return u;
}
__device__ __forceinline__ unsigned pk2bf(float a, float b) { // -> v_cvt_pk_bf16_f32
    return (unsigned)s2bf(a) | ((unsigned)s2bf(b) << 16);
}

__device__ __forceinline__ void stage_chunk(unsigned char* xt, int w, int c, float4 v, int l) {
    int pt   = w * 32 + c * 4 + (l >> 4);
    int colB = (l & 15) * 8;
    int swz  = (pt & 15) << 4;
    uint2 bx, bx2;
    bx.x  = pk2bf(v.x, v.y);              bx.y  = pk2bf(v.z, v.w);
    bx2.x = pk2bf(v.x * v.x, v.y * v.y);  bx2.y = pk2bf(v.z * v.z, v.w * v.w);
    *(uint2*)(xt + pt * 256 + (colB ^ swz))         = bx;
    *(uint2*)(xt + pt * 256 + ((128 + colB) ^ swz)) = bx2;
}

__global__ __launch_bounds__(256, 2)
void gmm_main(const float* __restrict__ X, const float* __restrict__ mu,
              const float* __restrict__ var, const float* __restrict__ pi,
              float* __restrict__ partials, int g) {
    __shared__ unsigned char smem[SMEM_BYTES];

    const int tid = threadIdx.x;
    const int l   = tid & 63;
    const int w   = tid >> 6;
    const int lm  = l & 31;
    const int lh  = l >> 5;
    const int mypt = w * 32 + lm;

    const float4* X4 = (const float4*)X;

    // ---- issue tile-0 loads first (latency hides under the prologue compute) ----
    float4 xr[8];
    {
        const float4* xs = X4 + (size_t)blockIdx.x * 2048 + w * 512;
#pragma unroll
        for (int c = 0; c < 8; ++c) xr[c] = xs[c * 64 + l];
    }

    // ---- prologue: W -> Wl (swizzled) + C -> cl, all in-kernel ----
    {
        int comp = tid >> 3, i8 = tid & 7;       // thread owns k in [i8*16, i8*16+16)
        unsigned char* wrow = smem + WL_BASE + comp * 256;
        int swz = (comp & 15) << 4;
        if (i8 < 4) {                            // k < 64 : W = mu/var
            int d0 = i8 * 16;
            const float* mm = mu  + comp * DIM + d0;
            const float* vv = var + comp * DIM + d0;
#pragma unroll
            for (int j = 0; j < 8; ++j) {
                unsigned u = pk2bf(mm[2*j] / vv[2*j], mm[2*j+1] / vv[2*j+1]);
                int k = d0 + 2 * j;
                *(unsigned*)(wrow + ((k * 2) ^ swz)) = u;
            }
        } else {                                 // k >= 64 : W = -0.5/var
            int d0 = (i8 - 4) * 16;
            const float* vv = var + comp * DIM + d0;
#pragma unroll
            for (int j = 0; j < 8; ++j) {
                unsigned u = pk2bf(-0.5f / vv[2*j], -0.5f / vv[2*j+1]);
                int k = 64 + d0 + 2 * j;
                *(unsigned*)(wrow + ((k * 2) ^ swz)) = u;
            }
        }
        // C partial sums into clp (overlay on dead xt)
        float* clp = (float*)smem;
        const float* vv = var + comp * DIM + i8 * 8;
        const float* mm = mu  + comp * DIM + i8 * 8;
        float p = 0.0f;
#pragma unroll
        for (int j = 0; j < 8; ++j) { float v = vv[j], m2 = mm[j]; p += m2 * m2 / v + logf(v); }
        clp[tid] = p;
    }
    __syncthreads();
    if (tid < KC) {
        float* clp = (float*)smem;
        float ssum = 0.0f;
#pragma unroll
        for (int j = 0; j < 8; ++j) ssum += clp[tid * 8 + j];
        const float LOG2PI = 1.8378770664093453f;
        ((float*)(smem + CL_BASE))[tid] = logf(pi[tid]) - 0.5f * (ssum + DIM * LOG2PI);
    }
    __syncthreads();   // Wl + cl ready; clp dead; xt free

    const float* cl = (const float*)(smem + CL_BASE);

    short8v onesf;                 // bf16 1.0 fragment for dem-MFMA
#pragma unroll
    for (int j = 0; j < 8; ++j) onesf[j] = (short)0x3F80;

    f32x16 rxacc, demA;
#pragma unroll
    for (int i = 0; i < 16; ++i) { rxacc[i] = 0.0f; demA[i] = 0.0f; }

    for (int tile = blockIdx.x; tile < NTILES; tile += g) {
        // ---- stage this wave's 32 rows from prefetched regs (wave-private) ----
#pragma unroll
        for (int c = 0; c < 8; ++c) stage_chunk(smem, w, c, xr[c], l);

        // ---- GEMM-1: S[comp][pt] = sum_d2 W[comp][d2] * xt[pt][d2] ----
        f32x16 s;
#pragma unroll
        for (int r = 0; r < 16; ++r) s[r] = 0.0f;
#pragma unroll
        for (int ks = 0; ks < 8; ++ks) {
            short8v a = *(const short8v*)(smem + WL_BASE + lm * 256 +
                                          ((ks * 32 + lh * 16) ^ ((lm & 15) << 4)));
            short8v b = *(const short8v*)(smem + mypt * 256 +
                                          ((ks * 32 + lh * 16) ^ ((lm & 15) << 4)));
            s = __builtin_amdgcn_mfma_f32_32x32x16_bf16(a, b, s, 0, 0, 0);
        }

        // ---- softmax over 32 comps for pt=mypt (lane pair l, l^32) ----
#pragma unroll
        for (int r = 0; r < 16; ++r) s[r] += cl[(r & 3) + 8 * (r >> 2) + 4 * lh];
        float m = s[0];
#pragma unroll
        for (int r = 1; r < 16; ++r) m = fmaxf(m, s[r]);
        m = fmaxf(m, __shfl_xor(m, 32, 64));
        float sum = 0.0f;
#pragma unroll
        for (int r = 0; r < 16; ++r) { s[r] = __expf(s[r] - m); sum += s[r]; }
        sum += __shfl_xor(sum, 32, 64);
        float inv = 1.0f / sum;
#pragma unroll
        for (int r = 0; r < 16; ++r) {
            float rv = s[r] * inv;
            int comp = (r & 3) + 8 * (r >> 2) + 4 * lh;
            *(unsigned short*)(smem + RL_BASE + comp * 256 +
                               ((mypt * 2) ^ ((comp & 15) << 4))) = s2bf(rv);
        }
        __syncthreads();   // barrier-1: xt + rl complete for all 128 pts

        // ---- prefetch next tile into regs; latency hides under GEMM-2,
        //      vmcnt drain happens at barrier-2 (after ~1200cyc of GEMM-2) ----
        if (tile + g < NTILES) {
            const float4* xs = X4 + (size_t)(tile + g) * 2048 + w * 512;
#pragma unroll
            for (int c = 0; c < 8; ++c) xr[c] = xs[c * 64 + l];
        }

        // ---- GEMM-2: wave w owns d2 = mypt; dem via extra MFMA (B = ones) ----
#pragma unroll
        for (int ks = 0; ks < 8; ++ks) {
            short8v af = *(const short8v*)(smem + RL_BASE + lm * 256 +
                                           ((ks * 32 + lh * 16) ^ ((lm & 15) << 4)));
            short8v bv;
#pragma unroll
            for (int j = 0; j < 8; ++j) {
                int pt = ks * 16 + lh * 8 + j;
                bv[j] = *(const short*)(smem + pt * 256 +
                                        ((mypt * 2) ^ ((pt & 15) << 4)));
            }
            rxacc = __builtin_amdgcn_mfma_f32_32x32x16_bf16(af, bv, rxacc, 0, 0, 0);
            demA  = __builtin_amdgcn_mfma_f32_32x32x16_bf16(af, onesf, demA, 0, 0, 0);
        }
        __syncthreads();   // barrier-2: xt/rl free for next tile
    }

    // ---- store partials: waves own disjoint d2 ----
    float* P = partials + (size_t)blockIdx.x * PROW;
#pragma unroll
    for (int r = 0; r < 16; ++r) {
        int comp = (r & 3) + 8 * (r >> 2) + 4 * lh;
        P[32 + comp * 128 + w * 32 + lm] = rxacc[r];
    }
    if (w == 0 && lm == 0) {       // lanes 0 and 32; demA cols all equal
#pragma unroll
        for (int r = 0; r < 16; ++r)
            P[(r & 3) + 8 * (r >> 2) + 4 * lh] = demA[r];
    }
}

__global__ __launch_bounds__(512)
void gmm_reduce(const float* __restrict__ partials, float* __restrict__ out, int nb) {
    __shared__ float red[512 * 4];
    __shared__ float dred[512];
    __shared__ float rxf[128];
    const int k = blockIdx.x;
    const int t = threadIdx.x;
    const int f4i   = t & 31;
    const int chunk = t >> 5;

    float4 s4 = {0.f, 0.f, 0.f, 0.f};
    const int R = nb >> 4;
#pragma unroll 4
    for (int j = 0; j < R; ++j) {
        int b = chunk * R + j;
        float4 v = *((const float4*)(partials + (size_t)b * PROW + 32 + k * 128) + f4i);
        s4.x += v.x; s4.y += v.y; s4.z += v.z; s4.w += v.w;
    }
    float dp = 0.0f;
    for (int b = t; b < nb; b += 512) dp += partials[(size_t)b * PROW + k];

    *(float4*)(red + t * 4) = s4;
    dred[t] = dp;
    __syncthreads();
    for (int off = 256; off >= 1; off >>= 1) {
        if (t < off) dred[t] += dred[t + off];
        __syncthreads();
    }
    if (t < 32) {
        float4 a = {0.f, 0.f, 0.f, 0.f};
#pragma unroll
        for (int c = 0; c < 16; ++c) {
            float4 v = *(const float4*)(red + (c * 32 + t) * 4);
            a.x += v.x; a.y += v.y; a.z += v.z; a.w += v.w;
        }
        *(float4*)(rxf + t * 4) = a;
    }
    __syncthreads();
    float dem = dred[0];
    if (t < 64) {
        float inv = 1.0f / dem;
        float rx  = rxf[t];
        float rx2 = rxf[t + 64];
        float muv = rx * inv;
        float va  = rx2 * inv - muv * muv;
        out[k * 129 + 1 + t]  = muv;
        out[k * 129 + 65 + t] = va;
        if (t == 0) out[k * 129] = dem * (1.0f / (float)NPTS);
    }
}

extern "C" void kernel_launch(void* const* d_in, const int* in_sizes, int n_in,
                              void* d_out, int out_size, void* d_ws, size_t ws_size,
                              hipStream_t stream) {
    const float* X   = (const float*)d_in[0];
    const float* mu  = (const float*)d_in[1];
    const float* var = (const float*)d_in[2];
    const float* pi  = (const float*)d_in[3];

    float* partials = (float*)d_ws;
    float* out      = (float*)d_out;

    int g = GRIDX;    // halving keeps nb % 16 == 0
    while (g > 96 && (size_t)g * PROW * 4 > ws_size) g >>= 1;

    gmm_main<<<g, 256, 0, stream>>>(X, mu, var, pi, partials, g);
    gmm_reduce<<<KC, 512, 0, stream>>>(partials, out, g);
}

// Round 17
// 40.379 us; speedup vs baseline: 1.1533x; 1.1533x over previous
//
#include <hip/hip_runtime.h>
#include <hip/hip_bf16.h>
#include <math.h>
#include <string.h>

#define NPTS 524288
#define KC 32
#define DIM 64
#define NTILES 4096        // NPTS / 128 points per block-tile
#define PROW 4128          // partial row: 32 dem + 32*128 rx
#define GRIDX 512          // 8 tiles/block uniform; 2 blocks/CU resident

typedef __attribute__((ext_vector_type(8)))  short short8v;
typedef __attribute__((ext_vector_type(16))) float f32x16;

// LDS byte map (per block), total 49280 B:
//   xt  @0      [128 pt][256B]  byte = pt*256  + (colB ^ ((pt&15)<<4))    (bf16 x | x^2)
//   rl  @32768  [32 comp][256B] byte = comp*256 + ((pt*2) ^ ((comp&15)<<4)) (bf16 r)
//   Wl  @40960  [32 comp][256B] byte = comp*256 + ((k*2) ^ ((comp&15)<<4))  (bf16 W)
//   cl  @49152  float[32]
// prologue: clp[256] scratch overlays xt[0..1024)
#define RL_BASE  32768
#define WL_BASE  40960
#define CL_BASE  49152
#define SMEM_BYTES 49280

__device__ __forceinline__ unsigned short s2bf(float a) {
    __hip_bfloat16 h = __float2bfloat16(a);
    unsigned short u;
    memcpy(&u, &h, 2);
    return u;
}
__device__ __forceinline__ unsigned pk2bf(float a, float b) { // -> v_cvt_pk_bf16_f32
    return (unsigned)s2bf(a) | ((unsigned)s2bf(b) << 16);
}

__device__ __forceinline__ void stage_chunk(unsigned char* xt, int w, int c, float4 v, int l) {
    int pt   = w * 32 + c * 4 + (l >> 4);
    int colB = (l & 15) * 8;
    int swz  = (pt & 15) << 4;
    uint2 bx, bx2;
    bx.x  = pk2bf(v.x, v.y);              bx.y  = pk2bf(v.z, v.w);
    bx2.x = pk2bf(v.x * v.x, v.y * v.y);  bx2.y = pk2bf(v.z * v.z, v.w * v.w);
    *(uint2*)(xt + pt * 256 + (colB ^ swz))         = bx;
    *(uint2*)(xt + pt * 256 + ((128 + colB) ^ swz)) = bx2;
}

__global__ __launch_bounds__(256, 2)
void gmm_main(const float* __restrict__ X, const float* __restrict__ mu,
              const float* __restrict__ var, const float* __restrict__ pi,
              float* __restrict__ partials, int g) {
    __shared__ unsigned char smem[SMEM_BYTES];

    const int tid = threadIdx.x;
    const int l   = tid & 63;
    const int w   = tid >> 6;
    const int lm  = l & 31;
    const int lh  = l >> 5;
    const int mypt = w * 32 + lm;

    const float4* X4 = (const float4*)X;

    // ---- issue tile-0 loads first (latency hides under the prologue compute) ----
    float4 xr[8];
    {
        const float4* xs = X4 + (size_t)blockIdx.x * 2048 + w * 512;
#pragma unroll
        for (int c = 0; c < 8; ++c) xr[c] = xs[c * 64 + l];
    }

    // ---- prologue: W -> Wl (swizzled) + C -> cl, all in-kernel ----
    {
        int comp = tid >> 3, i8 = tid & 7;       // thread owns k in [i8*16, i8*16+16)
        unsigned char* wrow = smem + WL_BASE + comp * 256;
        int swz = (comp & 15) << 4;
        if (i8 < 4) {                            // k < 64 : W = mu/var
            int d0 = i8 * 16;
            const float* mm = mu  + comp * DIM + d0;
            const float* vv = var + comp * DIM + d0;
#pragma unroll
            for (int j = 0; j < 8; ++j) {
                unsigned u = pk2bf(mm[2*j] / vv[2*j], mm[2*j+1] / vv[2*j+1]);
                int k = d0 + 2 * j;
                *(unsigned*)(wrow + ((k * 2) ^ swz)) = u;
            }
        } else {                                 // k >= 64 : W = -0.5/var
            int d0 = (i8 - 4) * 16;
            const float* vv = var + comp * DIM + d0;
#pragma unroll
            for (int j = 0; j < 8; ++j) {
                unsigned u = pk2bf(-0.5f / vv[2*j], -0.5f / vv[2*j+1]);
                int k = 64 + d0 + 2 * j;
                *(unsigned*)(wrow + ((k * 2) ^ swz)) = u;
            }
        }
        // C partial sums into clp (overlay on dead xt)
        float* clp = (float*)smem;
        const float* vv = var + comp * DIM + i8 * 8;
        const float* mm = mu  + comp * DIM + i8 * 8;
        float p = 0.0f;
#pragma unroll
        for (int j = 0; j < 8; ++j) { float v = vv[j], m2 = mm[j]; p += m2 * m2 / v + logf(v); }
        clp[tid] = p;
    }
    __syncthreads();
    if (tid < KC) {
        float* clp = (float*)smem;
        float ssum = 0.0f;
#pragma unroll
        for (int j = 0; j < 8; ++j) ssum += clp[tid * 8 + j];
        const float LOG2PI = 1.8378770664093453f;
        ((float*)(smem + CL_BASE))[tid] = logf(pi[tid]) - 0.5f * (ssum + DIM * LOG2PI);
    }
    __syncthreads();   // Wl + cl ready; clp dead; xt free

    const float* cl = (const float*)(smem + CL_BASE);

    short8v onesf;                 // bf16 1.0 fragment for dem-MFMA
#pragma unroll
    for (int j = 0; j < 8; ++j) onesf[j] = (short)0x3F80;

    f32x16 rxacc, demA;
#pragma unroll
    for (int i = 0; i < 16; ++i) { rxacc[i] = 0.0f; demA[i] = 0.0f; }

    for (int tile = blockIdx.x; tile < NTILES; tile += g) {
        // ---- stage this wave's 32 rows from prefetched regs (wave-private) ----
#pragma unroll
        for (int c = 0; c < 8; ++c) stage_chunk(smem, w, c, xr[c], l);

        // ---- issue next-tile loads NOW (xr regs just freed). They stay in
        //      flight across the raw barrier-1; drained only at barrier-2,
        //      a full GEMM1+softmax+GEMM2 (~7k cyc) later -> HBM streams. ----
        if (tile + g < NTILES) {
            const float4* xs = X4 + (size_t)(tile + g) * 2048 + w * 512;
#pragma unroll
            for (int c = 0; c < 8; ++c) xr[c] = xs[c * 64 + l];
        }

        // ---- GEMM-1: reads only this wave's own staged rows (no barrier) ----
        f32x16 s;
#pragma unroll
        for (int r = 0; r < 16; ++r) s[r] = 0.0f;
#pragma unroll
        for (int ks = 0; ks < 8; ++ks) {
            short8v a = *(const short8v*)(smem + WL_BASE + lm * 256 +
                                          ((ks * 32 + lh * 16) ^ ((lm & 15) << 4)));
            short8v b = *(const short8v*)(smem + mypt * 256 +
                                          ((ks * 32 + lh * 16) ^ ((lm & 15) << 4)));
            s = __builtin_amdgcn_mfma_f32_32x32x16_bf16(a, b, s, 0, 0, 0);
        }

        // ---- softmax over 32 comps for pt=mypt (lane pair l, l^32) ----
#pragma unroll
        for (int r = 0; r < 16; ++r) s[r] += cl[(r & 3) + 8 * (r >> 2) + 4 * lh];
        float m = s[0];
#pragma unroll
        for (int r = 1; r < 16; ++r) m = fmaxf(m, s[r]);
        m = fmaxf(m, __shfl_xor(m, 32, 64));
        float sum = 0.0f;
#pragma unroll
        for (int r = 0; r < 16; ++r) { s[r] = __expf(s[r] - m); sum += s[r]; }
        sum += __shfl_xor(sum, 32, 64);
        float inv = 1.0f / sum;
#pragma unroll
        for (int r = 0; r < 16; ++r) {
            float rv = s[r] * inv;
            int comp = (r & 3) + 8 * (r >> 2) + 4 * lh;
            *(unsigned short*)(smem + RL_BASE + comp * 256 +
                               ((mypt * 2) ^ ((comp & 15) << 4))) = s2bf(rv);
        }

        // ---- barrier-1 (raw): drain LDS only; global loads stay in flight ----
        asm volatile("s_waitcnt lgkmcnt(0)" ::: "memory");
        __builtin_amdgcn_s_barrier();
        __builtin_amdgcn_sched_barrier(0);

        // ---- GEMM-2: wave w owns d2 = mypt; dem via extra MFMA (B = ones) ----
#pragma unroll
        for (int ks = 0; ks < 8; ++ks) {
            short8v af = *(const short8v*)(smem + RL_BASE + lm * 256 +
                                           ((ks * 32 + lh * 16) ^ ((lm & 15) << 4)));
            short8v bv;
#pragma unroll
            for (int j = 0; j < 8; ++j) {
                int pt = ks * 16 + lh * 8 + j;
                bv[j] = *(const short*)(smem + pt * 256 +
                                        ((mypt * 2) ^ ((pt & 15) << 4)));
            }
            rxacc = __builtin_amdgcn_mfma_f32_32x32x16_bf16(af, bv, rxacc, 0, 0, 0);
            demA  = __builtin_amdgcn_mfma_f32_32x32x16_bf16(af, onesf, demA, 0, 0, 0);
        }
        __syncthreads();   // barrier-2: drains vmcnt (window = full tile) + lgkm
    }

    // ---- store partials: waves own disjoint d2 ----
    float* P = partials + (size_t)blockIdx.x * PROW;
#pragma unroll
    for (int r = 0; r < 16; ++r) {
        int comp = (r & 3) + 8 * (r >> 2) + 4 * lh;
        P[32 + comp * 128 + w * 32 + lm] = rxacc[r];
    }
    if (w == 0 && lm == 0) {       // lanes 0 and 32; demA cols all equal
#pragma unroll
        for (int r = 0; r < 16; ++r)
            P[(r & 3) + 8 * (r >> 2) + 4 * lh] = demA[r];
    }
}

__global__ __launch_bounds__(512)
void gmm_reduce(const float* __restrict__ partials, float* __restrict__ out, int nb) {
    __shared__ float red[512 * 4];
    __shared__ float dred[512];
    __shared__ float rxf[128];
    const int k = blockIdx.x;
    const int t = threadIdx.x;
    const int f4i   = t & 31;
    const int chunk = t >> 5;

    float4 s4 = {0.f, 0.f, 0.f, 0.f};
    const int R = nb >> 4;
#pragma unroll 4
    for (int j = 0; j < R; ++j) {
        int b = chunk * R + j;
        float4 v = *((const float4*)(partials + (size_t)b * PROW + 32 + k * 128) + f4i);
        s4.x += v.x; s4.y += v.y; s4.z += v.z; s4.w += v.w;
    }
    float dp = 0.0f;
    for (int b = t; b < nb; b += 512) dp += partials[(size_t)b * PROW + k];

    *(float4*)(red + t * 4) = s4;
    dred[t] = dp;
    __syncthreads();
    for (int off = 256; off >= 1; off >>= 1) {
        if (t < off) dred[t] += dred[t + off];
        __syncthreads();
    }
    if (t < 32) {
        float4 a = {0.f, 0.f, 0.f, 0.f};
#pragma unroll
        for (int c = 0; c < 16; ++c) {
            float4 v = *(const float4*)(red + (c * 32 + t) * 4);
            a.x += v.x; a.y += v.y; a.z += v.z; a.w += v.w;
        }
        *(float4*)(rxf + t * 4) = a;
    }
    __syncthreads();
    float dem = dred[0];
    if (t < 64) {
        float inv = 1.0f / dem;
        float rx  = rxf[t];
        float rx2 = rxf[t + 64];
        float muv = rx * inv;
        float va  = rx2 * inv - muv * muv;
        out[k * 129 + 1 + t]  = muv;
        out[k * 129 + 65 + t] = va;
        if (t == 0) out[k * 129] = dem * (1.0f / (float)NPTS);
    }
}

extern "C" void kernel_launch(void* const* d_in, const int* in_sizes, int n_in,
                              void* d_out, int out_size, void* d_ws, size_t ws_size,
                              hipStream_t stream) {
    const float* X   = (const float*)d_in[0];
    const float* mu  = (const float*)d_in[1];
    const float* var = (const float*)d_in[2];
    const float* pi  = (const float*)d_in[3];

    float* partials = (float*)d_ws;
    float* out      = (float*)d_out;

    int g = GRIDX;    // halving keeps nb % 16 == 0
    while (g > 64 && (size_t)g * PROW * 4 > ws_size) g >>= 1;

    gmm_main<<<g, 256, 0, stream>>>(X, mu, var, pi, partials, g);
    gmm_reduce<<<KC, 512, 0, stream>>>(partials, out, g);
}